// Round 5
// baseline (236.368 us; speedup 1.0000x reference)
//
#include <hip/hip_runtime.h>

namespace {
constexpr int B = 16, C = 19, H = 512, W = 512;
constexpr int TPB = 128;                     // 2 waves; thread t owns cols 4t..4t+3 (full 512)
constexpr int H_CHUNK = 64;
constexpr int NHC = H / H_CHUNK;             // 8
constexpr int NXCD = 8;
constexpr int TILES = B * NHC;               // 128 (b,hc) target tiles
constexpr int TILES_PER_XCD = TILES / NXCD;  // 16
constexpr int TOTAL_BLOCKS = TILES * C;      // 2432 = 8 * 304 (swizzle bijective)
constexpr float SCALE = 1.0f / (float)((long long)B * H * W);
}

// Per-row separable-Sobel aggregates for 4 owned columns (input d,s; mask e,u):
//   d[j] = x[j+1]-x[j-1]; s[j] = x[j-1]+2x[j]+x[j+1];  e,u same on one-hot mask.
//   gx = d(h-1)+2d(h)+d(h+1); gy = s(h+1)-s(h-1); likewise hx,hy from e,u.
struct RowA { float4 d, s, e, u; };

__global__ void zero_out_kernel(float* out) { *out = 0.0f; }

__global__ __launch_bounds__(TPB) void edge_loss_kernel(
    const float* __restrict__ X,   // [B,C,H,W] f32
    const int*   __restrict__ T,   // [B,H,W] int32 labels
    float* __restrict__ out)
{
    // XCD swizzle: bid%8 -> XCD. Group all 19 class-blocks of one (b,hc) tile
    // consecutively on ONE XCD so the T tile is fetched into its L2 once.
    int i = (int)blockIdx.x;
    const int xcd  = i & (NXCD - 1);
    const int j    = i >> 3;
    const int c    = j % C;
    const int tl   = j / C;
    const int tile = xcd * TILES_PER_XCD + tl;
    const int b    = tile >> 3;                // tile / NHC
    const int hc   = tile & (NHC - 1);

    const int tid  = (int)threadIdx.x;
    const int lane = tid & 63;
    const int w0   = tid << 2;                 // first of 4 owned columns
    const int h0   = hc * H_CHUNK;

    const bool imgL = (w0 == 0);               // image left border (tid 0)
    const bool imgR = (w0 + 4 == W);           // image right border (tid 127)

    const float* __restrict__ Xs = X + (size_t)(b * C + c) * (size_t)(H * W);
    const int*   __restrict__ Ts = T + (size_t)b * (size_t)(H * W);

    RowA r0, r1, r2;
    float4 acc = make_float4(0.f, 0.f, 0.f, 0.f);

    auto zero_row = [&](RowA& r) {
        r.d = r.s = r.e = r.u = make_float4(0.f, 0.f, 0.f, 0.f);
    };

    auto ldrow = [&](RowA& r, const float* xrow, const int* trow) {
        const float4 xv = *reinterpret_cast<const float4*>(xrow + w0);
        const int4   tv = *reinterpret_cast<const int4*>(trow + w0);

        // halo columns w0-1 / w0+4 from neighbor lanes' vector edges
        float xm  = __shfl_up(xv.w, 1, 64);
        float xp  = __shfl_down(xv.x, 1, 64);
        int   tmh = __shfl_up(tv.w, 1, 64);
        int   tph = __shfl_down(tv.x, 1, 64);
        // wave-seam / image-border patches (1 active lane each)
        if (lane == 0) {                       // tid 0 (border) or tid 64 (seam)
            const int a  = imgL ? 0 : (w0 - 1);
            const float xx = xrow[a];
            const int   tt = trow[a];
            xm  = imgL ? 0.0f : xx;            // zero-pad
            tmh = imgL ? -1   : tt;            // -1 never equals c
        }
        if (lane == 63) {                      // tid 63 (seam) or tid 127 (border)
            const int a  = imgR ? 0 : (w0 + 4);
            const float xx = xrow[a];
            const int   tt = trow[a];
            xp  = imgR ? 0.0f : xx;
            tph = imgR ? -1   : tt;
        }

        // 6 label compares serve all 4 columns
        const float mm = (tmh  == c) ? 1.f : 0.f;
        const float m0 = (tv.x == c) ? 1.f : 0.f;
        const float m1 = (tv.y == c) ? 1.f : 0.f;
        const float m2 = (tv.z == c) ? 1.f : 0.f;
        const float m3 = (tv.w == c) ? 1.f : 0.f;
        const float mp = (tph  == c) ? 1.f : 0.f;

        r.d.x = xv.y - xm;   r.d.y = xv.z - xv.x;
        r.d.z = xv.w - xv.y; r.d.w = xp   - xv.z;
        r.s.x = fmaf(2.f, xv.x, xm   + xv.y);
        r.s.y = fmaf(2.f, xv.y, xv.x + xv.z);
        r.s.z = fmaf(2.f, xv.z, xv.y + xv.w);
        r.s.w = fmaf(2.f, xv.w, xv.z + xp);

        r.e.x = m1 - mm; r.e.y = m2 - m0;
        r.e.z = m3 - m1; r.e.w = mp - m2;
        r.u.x = fmaf(2.f, m0, mm + m1);
        r.u.y = fmaf(2.f, m1, m0 + m2);
        r.u.z = fmaf(2.f, m2, m1 + m3);
        r.u.w = fmaf(2.f, m3, m2 + mp);
    };

    auto comp = [&](const RowA& ra, const RowA& rb, const RowA& rc) {
#define CMP1(f)                                                        \
        {                                                              \
            const float gx = fmaf(2.f, rb.d.f, ra.d.f + rc.d.f);       \
            const float gy = rc.s.f - ra.s.f;                          \
            const float hx = fmaf(2.f, rb.e.f, ra.e.f + rc.e.f);       \
            const float hy = rc.u.f - ra.u.f;                          \
            const float dd = (fabsf(gx) + fabsf(gy))                   \
                           - (fabsf(hx) + fabsf(hy));                  \
            acc.f = fmaf(dd, dd, acc.f);                               \
        }
        CMP1(x) CMP1(y) CMP1(z) CMP1(w)
#undef CMP1
    };

    const float* xr = Xs + (size_t)h0 * W;
    const int*   tr = Ts + (size_t)h0 * W;

    // prologue: row h0-1 (block-uniform) and row h0
    if (hc == 0) zero_row(r0);
    else         ldrow(r0, xr - W, tr - W);
    ldrow(r1, xr, tr);

    // 63 branch-free outputs h0..h0+62 (loads rows h0+1..h0+63, all in range)
#define STEP(ra, rb, rc)                        \
    {                                           \
        xr += W; tr += W;                       \
        ldrow(rc, xr, tr);                      \
        comp(ra, rb, rc);                       \
    }
    for (int t = 0; t < 21; ++t) {
        STEP(r0, r1, r2)
        STEP(r1, r2, r0)
        STEP(r2, r0, r1)
    }
#undef STEP
    // final output h0+63 needs row h0+64 (OOB only for last chunk)
    if (hc == NHC - 1) zero_row(r2);
    else { xr += W; tr += W; ldrow(r2, xr, tr); }
    comp(r0, r1, r2);

    // reduce: fold 4 cols, wave shuffle, 2 waves via LDS, one atomic per block
    float a = (acc.x + acc.y) + (acc.z + acc.w);
    #pragma unroll
    for (int off = 32; off > 0; off >>= 1)
        a += __shfl_down(a, off, 64);

    __shared__ float wsum[TPB / 64];
    const int wid = tid >> 6;
    if (lane == 0) wsum[wid] = a;
    __syncthreads();
    if (tid == 0) atomicAdd(out, (wsum[0] + wsum[1]) * SCALE);
}

extern "C" void kernel_launch(void* const* d_in, const int* in_sizes, int n_in,
                              void* d_out, int out_size, void* d_ws, size_t ws_size,
                              hipStream_t stream) {
    (void)in_sizes; (void)n_in; (void)d_ws; (void)ws_size; (void)out_size;
    const float* X = (const float*)d_in[0];
    const int*   T = (const int*)d_in[1];
    float* out = (float*)d_out;

    zero_out_kernel<<<1, 1, 0, stream>>>(out);
    edge_loss_kernel<<<TOTAL_BLOCKS, TPB, 0, stream>>>(X, T, out);
}

// Round 6
// 110.365 us; speedup vs baseline: 2.1417x; 2.1417x over previous
//
#include <hip/hip_runtime.h>

namespace {
constexpr int B = 16, C = 19, H = 512, W = 512;
constexpr int TPB = 128;               // 2 waves; thread t owns cols 4t..4t+3
constexpr int HC = 32;                 // output rows per block
constexpr int NHC = H / HC;            // 16
constexpr int NXCD = 8;
constexpr int TILES = B * NHC;         // 256 (b,hc) target tiles
constexpr int TPX = TILES / NXCD;      // 32
constexpr int NBLK = TILES * C;        // 4864 = 8*608 (XCD swizzle bijective)
constexpr float SCALE = 1.0f / (float)((long long)B * H * W);
}

// Raw per-row loads: 6 X values (cols colA..colA+3, colB..colB+1) + 6 labels.
struct Raw {
    float xa0, xa1, xa2, xa3, xb0, xb1;
    int   ta0, ta1, ta2, ta3, tb0, tb1;
};
// Separable-Sobel row aggregates for the 4 owned columns:
//   d = x[w+1]-x[w-1]; s = x[w-1]+2x[w]+x[w+1];  e,u same on one-hot mask.
//   gx = d(h-1)+2d(h)+d(h+1); gy = s(h+1)-s(h-1); hx,hy likewise from e,u.
struct Agg { float d0,d1,d2,d3, s0,s1,s2,s3, e0,e1,e2,e3, u0,u1,u2,u3; };

__global__ void zero_out_kernel(float* out) { *out = 0.0f; }

__global__ __launch_bounds__(TPB) void edge_loss_kernel(
    const float* __restrict__ X,   // [B,C,H,W] f32
    const int*   __restrict__ T,   // [B,H,W] int32 labels
    float* __restrict__ out)
{
    // XCD swizzle: bid%8 -> XCD. All 19 class-blocks of one (b,hc) tile go to
    // ONE XCD, adjacent in dispatch order -> T tile L2-resident, fetched once.
    int i = (int)blockIdx.x;
    const int xcd  = i & (NXCD - 1);
    const int j    = i >> 3;
    const int c    = j % C;
    const int tl   = j / C;
    const int tile = xcd * TPX + tl;
    const int b    = tile >> 4;            // / NHC
    const int hc   = tile & (NHC - 1);
    const int h0   = hc * HC;

    const int tid  = (int)threadIdx.x;
    const int w0   = tid << 2;
    const bool imgL = (tid == 0);
    const bool imgR = (tid == TPB - 1);
    const int colA = imgL ? 0 : (w0 - 1);          // 4-wide load base (never OOB)
    const int colB = imgR ? (w0 + 2) : (w0 + 3);   // 2-wide load base (never OOB)

    const float* __restrict__ Xs = X + (size_t)(b * C + c) * (size_t)(H * W);
    const int*   __restrict__ Ts = T + (size_t)b * (size_t)(H * W);

    const int r0 = (hc == 0) ? 0 : (h0 - 1);       // clamped first row
    const float* pxa = Xs + (size_t)r0 * W + colA;
    const float* pxb = Xs + (size_t)r0 * W + colB;
    const int*   pta = Ts + (size_t)r0 * W + colA;
    const int*   ptb = Ts + (size_t)r0 * W + colB;
    const int step1 = (hc == 0) ? 0 : W;

    auto issue = [&](Raw& q) {                     // 4 mergeable loads (x4,x2 ×2)
        q.xa0 = pxa[0]; q.xa1 = pxa[1]; q.xa2 = pxa[2]; q.xa3 = pxa[3];
        q.xb0 = pxb[0]; q.xb1 = pxb[1];
        q.ta0 = pta[0]; q.ta1 = pta[1]; q.ta2 = pta[2]; q.ta3 = pta[3];
        q.tb0 = ptb[0]; q.tb1 = ptb[1];
    };
    auto advance = [&](int dw) { pxa += dw; pxb += dw; pta += dw; ptb += dw; };

    auto aggregate = [&](Agg& g, const Raw& q) {
        // branchless border remap (masks are loop-invariant vcc pairs)
        const float xm = imgL ? 0.f   : q.xa0;
        const float x0 = imgL ? q.xa0 : q.xa1;
        const float x1 = imgL ? q.xa1 : q.xa2;
        const float x2 = imgL ? q.xa2 : q.xa3;
        const float x3 = imgR ? q.xb1 : q.xb0;
        const float xp = imgR ? 0.f   : q.xb1;
        const float nA = (q.ta0 == c) ? 1.f : 0.f;
        const float nB = (q.ta1 == c) ? 1.f : 0.f;
        const float nC = (q.ta2 == c) ? 1.f : 0.f;
        const float nD = (q.ta3 == c) ? 1.f : 0.f;
        const float nE = (q.tb0 == c) ? 1.f : 0.f;
        const float nF = (q.tb1 == c) ? 1.f : 0.f;
        const float mm = imgL ? 0.f : nA;
        const float m0 = imgL ? nA  : nB;
        const float m1 = imgL ? nB  : nC;
        const float m2 = imgL ? nC  : nD;
        const float m3 = imgR ? nF  : nE;
        const float mp = imgR ? 0.f : nF;
        g.d0 = x1 - xm; g.d1 = x2 - x0; g.d2 = x3 - x1; g.d3 = xp - x2;
        g.s0 = fmaf(2.f, x0, xm + x1); g.s1 = fmaf(2.f, x1, x0 + x2);
        g.s2 = fmaf(2.f, x2, x1 + x3); g.s3 = fmaf(2.f, x3, x2 + xp);
        g.e0 = m1 - mm; g.e1 = m2 - m0; g.e2 = m3 - m1; g.e3 = mp - m2;
        g.u0 = fmaf(2.f, m0, mm + m1); g.u1 = fmaf(2.f, m1, m0 + m2);
        g.u2 = fmaf(2.f, m2, m1 + m3); g.u3 = fmaf(2.f, m3, m2 + mp);
    };
    auto zagg = [&](Agg& g) {
        g.d0=g.d1=g.d2=g.d3 = g.s0=g.s1=g.s2=g.s3 =
        g.e0=g.e1=g.e2=g.e3 = g.u0=g.u1=g.u2=g.u3 = 0.f;
    };

    float ac0 = 0.f, ac1 = 0.f, ac2 = 0.f, ac3 = 0.f;
    auto comp = [&](const Agg& A, const Agg& Bb, const Agg& Cc) {
#define CM(k) {                                                     \
        const float gx = fmaf(2.f, Bb.d##k, A.d##k + Cc.d##k);      \
        const float gy = Cc.s##k - A.s##k;                          \
        const float hx = fmaf(2.f, Bb.e##k, A.e##k + Cc.e##k);      \
        const float hy = Cc.u##k - A.u##k;                          \
        const float dd = (fabsf(gx) + fabsf(gy))                    \
                       - (fabsf(hx) + fabsf(hy));                   \
        ac##k = fmaf(dd, dd, ac##k); }
        CM(0) CM(1) CM(2) CM(3)
#undef CM
    };

    Raw qa, qb;
    Agg g0, g1, g2;

    // ---- pipeline prologue ----
    issue(qa);                    // row h0-1 (clamped to row 0 when hc==0)
    advance(step1);
    issue(qb);                    // row h0
    advance(W);
    aggregate(g0, qa);
    if (hc == 0) zagg(g0);        // zero-pad top border (block-uniform)
    issue(qa);                    // row h0+1
    advance(W);
    aggregate(g1, qb);

    // ---- steady state: iter t issues row h0+t+2, aggregates h0+t+1,
    //      combines output row h0+t.  t = 0..29, unroll 6 (buf parity 2 x rot 3)
#define PSTEP(QI, QC, GA, GB, GC) \
    issue(QI); advance(W);        \
    aggregate(GC, QC);            \
    comp(GA, GB, GC);

    for (int t6 = 0; t6 < 5; ++t6) {
        PSTEP(qb, qa, g0, g1, g2)
        PSTEP(qa, qb, g1, g2, g0)
        PSTEP(qb, qa, g2, g0, g1)
        PSTEP(qa, qb, g0, g1, g2)
        PSTEP(qb, qa, g1, g2, g0)
        PSTEP(qa, qb, g2, g0, g1)
    }
#undef PSTEP

    // ---- epilogue ----
    // t=30: issue row h0+32 (clamped for the last chunk), consume qa (row h0+31)
    {
        const int back = (hc == NHC - 1) ? W : 0;
        pxa -= back; pxb -= back; pta -= back; ptb -= back;
        issue(qb);
        aggregate(g2, qa);
        comp(g0, g1, g2);         // output row h0+30
    }
    // t=31: consume qb (row h0+32; zero-pad if below image)
    {
        aggregate(g0, qb);
        if (hc == NHC - 1) zagg(g0);
        comp(g1, g2, g0);         // output row h0+31
    }

    // ---- reduce: fold 4 cols -> wave shuffle -> LDS (2 waves) -> 1 atomic ----
    float a = (ac0 + ac1) + (ac2 + ac3);
    #pragma unroll
    for (int off = 32; off > 0; off >>= 1)
        a += __shfl_down(a, off, 64);

    __shared__ float wsum[TPB / 64];
    const int lane = tid & 63;
    const int wid  = tid >> 6;
    if (lane == 0) wsum[wid] = a;
    __syncthreads();
    if (tid == 0) atomicAdd(out, (wsum[0] + wsum[1]) * SCALE);
}

extern "C" void kernel_launch(void* const* d_in, const int* in_sizes, int n_in,
                              void* d_out, int out_size, void* d_ws, size_t ws_size,
                              hipStream_t stream) {
    (void)in_sizes; (void)n_in; (void)d_ws; (void)ws_size; (void)out_size;
    const float* X = (const float*)d_in[0];
    const int*   T = (const int*)d_in[1];
    float* out = (float*)d_out;

    zero_out_kernel<<<1, 1, 0, stream>>>(out);
    edge_loss_kernel<<<NBLK, TPB, 0, stream>>>(X, T, out);
}